// Round 4
// baseline (3151.835 us; speedup 1.0000x reference)
//
#include <hip/hip_runtime.h>
#include <hip/hip_bf16.h>

constexpr int B_ = 8, N_ = 2048, K_ = 20;
constexpr float EPS_ = 1e-5f;

// ---- weight area offsets (in floats) ----
constexpr int OW1T = 0;                    // W1^T  [512][256]
constexpr int OWST = OW1T + 512 * 256;     // Ws^T  [512][256]
constexpr int OW2T = OWST + 512 * 256;     // W2^T  [256][256]
constexpr int OWQT = OW2T + 256 * 256;     // wq^T  [256][64]
constexpr int OWKT = OWQT + 256 * 64;
constexpr int OWVT = OWKT + 256 * 64;
constexpr int OWUT = OWVT + 256 * 64;
constexpr int OWRT = OWUT + 256 * 64;      // wr^T  [256][128]
constexpr int OWET = OWRT + 256 * 128;     // we^T  [o][co] 64x128
constexpr int OWTC = OWET + 64 * 128;      // am_wt [c][o*2+r] 256x128 (native)
constexpr int OAW1 = OWTC + 256 * 128;     // am_w1 stored [o(64)][c(256)] = am_w1[c][o]
constexpr int OPW1 = OAW1 + 64 * 256;      // pm_w1 [ph][3]
constexpr int OPW2 = OPW1 + 64 * 3;        // pm_w2 [o][c] 64x64
constexpr int OB1  = OPW2 + 64 * 64;       // mv_b1 [256]
constexpr int OBS2 = OB1 + 256;            // mv_bs + mv_b2 [256]
constexpr int OBQ  = OBS2 + 256;
constexpr int OBK  = OBQ + 64;
constexpr int OBV  = OBK + 64;
constexpr int OBU  = OBV + 64;
constexpr int OBR  = OBU + 64;             // [128]
constexpr int OBE  = OBR + 128;            // [128]
constexpr int OPB1 = OBE + 128;            // [64]
constexpr int OPSC = OPB1 + 64;
constexpr int OPSH = OPSC + 64;
constexpr int OPB2 = OPSH + 64;
constexpr int OASC = OPB2 + 64;            // [256]
constexpr int OASH = OASC + 256;
constexpr int OAB1 = OASH + 256;
constexpr int OABT = OAB1 + 256;           // [64]

// ---- workspace byte offsets (28 MiB total) ----
constexpr size_t OFFB_WF   = 0;
constexpr size_t OFFB_IDX  = (size_t)2 << 20;
constexpr size_t OFFB_Q    = (size_t)4 << 20;
constexpr size_t OFFB_K    = (size_t)8 << 20;
constexpr size_t OFFB_U    = (size_t)12 << 20;
constexpr size_t OFFB_V    = (size_t)16 << 20;
constexpr size_t OFFB_IDEN = (size_t)20 << 20;

struct InPtrs { const float* p[38]; };

// ------------------------------------------------------------------
// Weight prep: transposes + BN folds (all f32)
// ------------------------------------------------------------------
__global__ __launch_bounds__(256) void k_prep(InPtrs in, float* __restrict__ wf) {
  const int tid = blockIdx.x * 256 + threadIdx.x;
  const int nth = gridDim.x * 256;
  const float *mv_w1 = in.p[4], *mv_b1 = in.p[5], *mv_w2 = in.p[6], *mv_b2 = in.p[7],
              *mv_ws = in.p[8], *mv_bs = in.p[9], *wk = in.p[10], *bk = in.p[11],
              *wq = in.p[12], *bq = in.p[13], *wv = in.p[14], *bv = in.p[15],
              *wu = in.p[16], *bu = in.p[17], *pm_w1 = in.p[18], *pm_b1 = in.p[19],
              *pm_g = in.p[20], *pm_be = in.p[21], *pm_m = in.p[22], *pm_v = in.p[23],
              *pm_w2 = in.p[24], *pm_b2 = in.p[25], *am_w1 = in.p[26], *am_b1 = in.p[27],
              *am_g = in.p[28], *am_be = in.p[29], *am_m = in.p[30], *am_v = in.p[31],
              *am_wt = in.p[32], *am_bt = in.p[33], *we = in.p[34], *be = in.p[35],
              *wr = in.p[36], *br = in.p[37];

  for (int i = tid; i < 512 * 256; i += nth) { int c = i >> 8, m = i & 255; wf[OW1T + i] = mv_w1[m * 512 + c]; }
  for (int i = tid; i < 512 * 256; i += nth) { int c = i >> 8, m = i & 255; wf[OWST + i] = mv_ws[m * 512 + c]; }
  for (int i = tid; i < 256 * 256; i += nth) { int c = i >> 8, m = i & 255; wf[OW2T + i] = mv_w2[m * 256 + c]; }
  for (int i = tid; i < 256 * 64; i += nth) { int c = i >> 6, m = i & 63; wf[OWQT + i] = wq[m * 256 + c]; }
  for (int i = tid; i < 256 * 64; i += nth) { int c = i >> 6, m = i & 63; wf[OWKT + i] = wk[m * 256 + c]; }
  for (int i = tid; i < 256 * 64; i += nth) { int c = i >> 6, m = i & 63; wf[OWVT + i] = wv[m * 256 + c]; }
  for (int i = tid; i < 256 * 64; i += nth) { int c = i >> 6, m = i & 63; wf[OWUT + i] = wu[m * 256 + c]; }
  for (int i = tid; i < 256 * 128; i += nth) { int c = i >> 7, m = i & 127; wf[OWRT + i] = wr[m * 256 + c]; }
  for (int i = tid; i < 64 * 128; i += nth) { int o = i >> 7, co = i & 127; wf[OWET + i] = we[co * 64 + o]; }
  for (int i = tid; i < 256 * 128; i += nth) wf[OWTC + i] = am_wt[i];
  for (int i = tid; i < 64 * 256; i += nth) { int o = i >> 8, c = i & 255; wf[OAW1 + i] = am_w1[c * 64 + o]; }
  for (int i = tid; i < 192; i += nth) wf[OPW1 + i] = pm_w1[i];
  for (int i = tid; i < 4096; i += nth) wf[OPW2 + i] = pm_w2[i];
  for (int i = tid; i < 256; i += nth) {
    wf[OB1 + i] = mv_b1[i];
    wf[OBS2 + i] = mv_bs[i] + mv_b2[i];
    float sc = am_g[i] / sqrtf(am_v[i] + EPS_);
    wf[OASC + i] = sc;
    wf[OASH + i] = am_be[i] - am_m[i] * sc;
    wf[OAB1 + i] = am_b1[i];
  }
  for (int i = tid; i < 64; i += nth) {
    wf[OBQ + i] = bq[i]; wf[OBK + i] = bk[i];
    wf[OBV + i] = bv[i]; wf[OBU + i] = bu[i];
    wf[OABT + i] = am_bt[i]; wf[OPB1 + i] = pm_b1[i]; wf[OPB2 + i] = pm_b2[i];
    float sc = pm_g[i] / sqrtf(pm_v[i] + EPS_);
    wf[OPSC + i] = sc;
    wf[OPSH + i] = pm_be[i] - pm_m[i] * sc;
  }
  for (int i = tid; i < 128; i += nth) { wf[OBR + i] = br[i]; wf[OBE + i] = be[i]; }
}

// ------------------------------------------------------------------
// Fused mv-MLP + v/iden projections. One block per (b, 16-col n-tile).
// hid & value stay in LDS (f32). 37 KB LDS/block.
// ------------------------------------------------------------------
__global__ __launch_bounds__(256) void k_mv(const float* __restrict__ wf,
                                            const float* __restrict__ keyf,
                                            const float* __restrict__ qryf,
                                            float* __restrict__ vout,
                                            float* __restrict__ idenout) {
  const int b = blockIdx.y;
  const int n0 = blockIdx.x * 16;
  __shared__ float hidL[256][16];  // 16 KB
  __shared__ float valL[256][16];  // 16 KB
  __shared__ float wsL[16][64];    // 4 KB
  __shared__ float xsL[16][16];    // 1 KB
  const int tid = threadIdx.x;
  const int tn = tid & 15, tm = tid >> 4;  // tn = col, tm = m-group

  // Phase 1: hid = relu(W1 [key;qry] + b1)
  for (int ms = 0; ms < 4; ++ms) {
    float acc[4] = {};
    for (int kt = 0; kt < 512; kt += 16) {
      for (int i = tid; i < 1024; i += 256) {
        int kk = i >> 6, col = i & 63;
        wsL[kk][col] = wf[OW1T + (size_t)(kt + kk) * 256 + ms * 64 + col];
      }
      {
        int kk = tid >> 4, col = tid & 15;
        int c = kt + kk;
        const float* s = (c < 256) ? keyf : qryf;
        xsL[kk][col] = s[((size_t)b * 256 + (c & 255)) * N_ + n0 + col];
      }
      __syncthreads();
#pragma unroll
      for (int kk = 0; kk < 16; ++kk) {
        float x = xsL[kk][tn];
#pragma unroll
        for (int i = 0; i < 4; ++i) acc[i] += wsL[kk][tm * 4 + i] * x;
      }
      __syncthreads();
    }
#pragma unroll
    for (int i = 0; i < 4; ++i)
      hidL[ms * 64 + tm * 4 + i][tn] = fmaxf(acc[i] + wf[OB1 + ms * 64 + tm * 4 + i], 0.f);
  }
  __syncthreads();

  // Phase 2: value = Ws [key;qry] + W2 hid + (bs + b2)
  for (int ms = 0; ms < 4; ++ms) {
    float acc[4] = {};
    for (int kt = 0; kt < 512; kt += 16) {
      for (int i = tid; i < 1024; i += 256) {
        int kk = i >> 6, col = i & 63;
        wsL[kk][col] = wf[OWST + (size_t)(kt + kk) * 256 + ms * 64 + col];
      }
      {
        int kk = tid >> 4, col = tid & 15;
        int c = kt + kk;
        const float* s = (c < 256) ? keyf : qryf;
        xsL[kk][col] = s[((size_t)b * 256 + (c & 255)) * N_ + n0 + col];
      }
      __syncthreads();
#pragma unroll
      for (int kk = 0; kk < 16; ++kk) {
        float x = xsL[kk][tn];
#pragma unroll
        for (int i = 0; i < 4; ++i) acc[i] += wsL[kk][tm * 4 + i] * x;
      }
      __syncthreads();
    }
    for (int kt = 0; kt < 256; kt += 16) {
      for (int i = tid; i < 1024; i += 256) {
        int kk = i >> 6, col = i & 63;
        wsL[kk][col] = wf[OW2T + (size_t)(kt + kk) * 256 + ms * 64 + col];
      }
      __syncthreads();
#pragma unroll
      for (int kk = 0; kk < 16; ++kk) {
        float x = hidL[kt + kk][tn];
#pragma unroll
        for (int i = 0; i < 4; ++i) acc[i] += wsL[kk][tm * 4 + i] * x;
      }
      __syncthreads();
    }
#pragma unroll
    for (int i = 0; i < 4; ++i)
      valL[ms * 64 + tm * 4 + i][tn] = acc[i] + wf[OBS2 + ms * 64 + tm * 4 + i];
  }
  __syncthreads();

  // Phase 3a: v = Wv value + bv
  {
    float acc[4] = {};
    for (int kt = 0; kt < 256; kt += 16) {
      for (int i = tid; i < 1024; i += 256) {
        int kk = i >> 6, col = i & 63;
        wsL[kk][col] = wf[OWVT + (size_t)(kt + kk) * 64 + col];
      }
      __syncthreads();
#pragma unroll
      for (int kk = 0; kk < 16; ++kk) {
        float x = valL[kt + kk][tn];
#pragma unroll
        for (int i = 0; i < 4; ++i) acc[i] += wsL[kk][tm * 4 + i] * x;
      }
      __syncthreads();
    }
#pragma unroll
    for (int i = 0; i < 4; ++i)
      vout[((size_t)b * 64 + tm * 4 + i) * N_ + n0 + tn] = acc[i] + wf[OBV + tm * 4 + i];
  }
  // Phase 3b: iden = Wr value + br
  for (int ms = 0; ms < 2; ++ms) {
    float acc[4] = {};
    for (int kt = 0; kt < 256; kt += 16) {
      for (int i = tid; i < 1024; i += 256) {
        int kk = i >> 6, col = i & 63;
        wsL[kk][col] = wf[OWRT + (size_t)(kt + kk) * 128 + ms * 64 + col];
      }
      __syncthreads();
#pragma unroll
      for (int kk = 0; kk < 16; ++kk) {
        float x = valL[kt + kk][tn];
#pragma unroll
        for (int i = 0; i < 4; ++i) acc[i] += wsL[kk][tm * 4 + i] * x;
      }
      __syncthreads();
    }
#pragma unroll
    for (int i = 0; i < 4; ++i)
      idenout[((size_t)b * 128 + ms * 64 + tm * 4 + i) * N_ + n0 + tn] =
          acc[i] + wf[OBR + ms * 64 + tm * 4 + i];
  }
}

// ------------------------------------------------------------------
// 64-out projection GEMM (q/k/u): out = Wt^T x + bias, x f32 [B][256][N]
// ------------------------------------------------------------------
__global__ __launch_bounds__(256) void k_gemm64(const float* __restrict__ Wt,
                                                const float* __restrict__ bias,
                                                const float* __restrict__ x,
                                                float* __restrict__ out) {
  const int b = blockIdx.z;
  const int n0 = blockIdx.x * 64;
  __shared__ float ws_[16][64];
  __shared__ float xs_[16][64];
  const int tid = threadIdx.x, tm = tid & 15, tn = tid >> 4;
  float acc[4][4] = {};
  for (int kt = 0; kt < 256; kt += 16) {
    for (int i = tid; i < 1024; i += 256) {
      int kk = i >> 6, col = i & 63;
      ws_[kk][col] = Wt[(size_t)(kt + kk) * 64 + col];
      xs_[kk][col] = x[((size_t)b * 256 + kt + kk) * N_ + n0 + col];
    }
    __syncthreads();
#pragma unroll
    for (int kk = 0; kk < 16; ++kk) {
      float xv0 = xs_[kk][tn * 4], xv1 = xs_[kk][tn * 4 + 1];
      float xv2 = xs_[kk][tn * 4 + 2], xv3 = xs_[kk][tn * 4 + 3];
#pragma unroll
      for (int i = 0; i < 4; ++i) {
        float w = ws_[kk][tm * 4 + i];
        acc[i][0] += w * xv0; acc[i][1] += w * xv1;
        acc[i][2] += w * xv2; acc[i][3] += w * xv3;
      }
    }
    __syncthreads();
  }
#pragma unroll
  for (int i = 0; i < 4; ++i) {
    float bi = bias[tm * 4 + i];
#pragma unroll
    for (int j = 0; j < 4; ++j)
      out[((size_t)b * 64 + tm * 4 + i) * N_ + n0 + tn * 4 + j] = acc[i][j] + bi;
  }
}

// ------------------------------------------------------------------
// Self-KNN in f64: d2 = sq_n + sq_m - 2*dot is essentially exact for
// f32 inputs -> true distance ordering. Top-20 min, tie -> lowest index.
// One block per (b,n).
// ------------------------------------------------------------------
__global__ __launch_bounds__(256) void k_knn(const float* __restrict__ pos, int* __restrict__ idxout) {
  const int b = blockIdx.x >> 11, n = blockIdx.x & 2047;
  __shared__ float px[2048], py[2048], pz[2048];
  __shared__ double psq[2048];
  __shared__ double d2s[2048];
  __shared__ double redd[4];
  __shared__ int redi[4];
  const int tid = threadIdx.x;
  for (int i = tid; i < 2048; i += 256) {
    float x = pos[((size_t)b * 3 + 0) * N_ + i];
    float y = pos[((size_t)b * 3 + 1) * N_ + i];
    float z = pos[((size_t)b * 3 + 2) * N_ + i];
    px[i] = x; py[i] = y; pz[i] = z;
    double xd = x, yd = y, zd = z;
    psq[i] = xd * xd + yd * yd + zd * zd;
  }
  __syncthreads();
  const double xq = px[n], yq = py[n], zq = pz[n], sq = psq[n];
  for (int i = tid; i < 2048; i += 256) {
    double dot = xq * (double)px[i] + yq * (double)py[i] + zq * (double)pz[i];
    d2s[i] = (sq + psq[i]) - 2.0 * dot;
  }
  __syncthreads();
  const int lane = tid & 63, wv = tid >> 6;
  for (int r = 0; r < K_; ++r) {
    double bd = __builtin_inf();
    int bi = 0x7FFFFFFF;
    for (int i = tid; i < 2048; i += 256) {
      double d = d2s[i];
      if (d < bd || (d == bd && i < bi)) { bd = d; bi = i; }
    }
#pragma unroll
    for (int off = 32; off; off >>= 1) {
      double od = __shfl_down(bd, off);
      int oi = __shfl_down(bi, off);
      if (od < bd || (od == bd && oi < bi)) { bd = od; bi = oi; }
    }
    if (lane == 0) { redd[wv] = bd; redi[wv] = bi; }
    __syncthreads();
    if (tid == 0) {
      double md = redd[0]; int mi = redi[0];
#pragma unroll
      for (int w = 1; w < 4; ++w)
        if (redd[w] < md || (redd[w] == md && redi[w] < mi)) { md = redd[w]; mi = redi[w]; }
      idxout[((size_t)b * N_ + n) * K_ + r] = mi & 2047;
      d2s[mi & 2047] = __builtin_inf();
    }
    __syncthreads();
  }
}

// ------------------------------------------------------------------
// Fused attention tail: one block per (b,n). ~56.8 KB LDS.
// ------------------------------------------------------------------
__global__ __launch_bounds__(256) void k_attn(
    const float* __restrict__ wf,
    const float* __restrict__ qb, const float* __restrict__ kb,
    const float* __restrict__ vb, const float* __restrict__ ub,
    const float* __restrict__ idenb, const int* __restrict__ idxb,
    const float* __restrict__ pos, float* __restrict__ out) {
  const int b = blockIdx.x >> 11, n = blockIdx.x & 2047;
  const int tid = threadIdx.x;
  __shared__ int idxs[20];
  __shared__ float qv[64], ufq[64], idv[128];
  __shared__ float kg[64][20], vg[64][20], ufg[64][20];
  __shared__ float prx[20], pry[20], prz[20];
  __shared__ float t1s[64][20];
  __shared__ float pes[64][20];
  __shared__ float hs[256][20];
  __shared__ float lg[128][20];
  __shared__ float aggs[128];

  if (tid < 20) idxs[tid] = idxb[((size_t)b * N_ + n) * K_ + tid] & 2047;
  if (tid >= 64 && tid < 128) qv[tid - 64] = qb[((size_t)b * 64 + (tid - 64)) * N_ + n];
  if (tid >= 128 && tid < 192) ufq[tid - 128] = ub[((size_t)b * 64 + (tid - 128)) * N_ + n];
  if (tid < 128) idv[tid] = idenb[((size_t)b * 128 + tid) * N_ + n];
  __syncthreads();

  for (int i = tid; i < 64 * 20; i += 256) {
    int o = i / 20, kk = i % 20;
    int j = idxs[kk];
    size_t base = ((size_t)b * 64 + o) * N_;
    kg[o][kk] = kb[base + j];
    vg[o][kk] = vb[base + j];
    ufg[o][kk] = ub[base + j];
  }
  if (tid < 20) {
    int j = idxs[tid];
    prx[tid] = pos[((size_t)b * 3 + 0) * N_ + n] - pos[((size_t)b * 3 + 0) * N_ + j];
    pry[tid] = pos[((size_t)b * 3 + 1) * N_ + n] - pos[((size_t)b * 3 + 1) * N_ + j];
    prz[tid] = pos[((size_t)b * 3 + 2) * N_ + n] - pos[((size_t)b * 3 + 2) * N_ + j];
  }
  __syncthreads();

  // pos-MLP layer 1 + BN + relu
  for (int i = tid; i < 64 * 20; i += 256) {
    int ph = i / 20, kk = i % 20;
    float u = wf[OPB1 + ph] + wf[OPW1 + ph * 3 + 0] * prx[kk] + wf[OPW1 + ph * 3 + 1] * pry[kk] +
              wf[OPW1 + ph * 3 + 2] * prz[kk];
    u = u * wf[OPSC + ph] + wf[OPSH + ph];
    t1s[ph][kk] = fmaxf(u, 0.f);
  }
  __syncthreads();

  // pos-MLP layer 2 -> pe
  for (int i = tid; i < 64 * 20; i += 256) {
    int o = i / 20, kk = i % 20;
    float a = wf[OPB2 + o];
    const float* w = wf + OPW2 + o * 64;
#pragma unroll 8
    for (int c = 0; c < 64; ++c) a += w[c] * t1s[c][kk];
    pes[o][kk] = a;
  }
  __syncthreads();

  // fold in place: kg <- s, vg <- val
  for (int i = tid; i < 64 * 20; i += 256) {
    int o = i / 20, kk = i % 20;
    float ur = ufq[o] - ufg[o][kk];
    float p = pes[o][kk];
    float s = (qv[o] - kg[o][kk]) + p + ur;
    float vv = vg[o][kk] + p + ur;
    kg[o][kk] = s;
    vg[o][kk] = vv;
  }
  __syncthreads();

  // h = relu(bn(am_w1 @ s + am_b1))
  {
    int c = tid;
    float acc[20] = {};
    const float* w = wf + OAW1 + c;
#pragma unroll 4
    for (int o = 0; o < 64; ++o) {
      float wo = w[o * 256];
#pragma unroll
      for (int kk = 0; kk < 20; ++kk) acc[kk] += wo * kg[o][kk];
    }
    float sc = wf[OASC + c], sh = wf[OASH + c], b1 = wf[OAB1 + c];
#pragma unroll
    for (int kk = 0; kk < 20; ++kk) hs[c][kk] = fmaxf((acc[kk] + b1) * sc + sh, 0.f);
  }
  __syncthreads();

  // logits[or][k] = sum_c h[c][k] * am_wt[c][or]
  {
    int orr = tid & 127, kh = tid >> 7;
    float acc[10] = {};
#pragma unroll 4
    for (int c = 0; c < 256; ++c) {
      float wv = wf[OWTC + c * 128 + orr];
#pragma unroll
      for (int t = 0; t < 10; ++t) acc[t] += wv * hs[c][kh * 10 + t];
    }
#pragma unroll
    for (int t = 0; t < 10; ++t) lg[orr][kh * 10 + t] = acc[t];
  }
  __syncthreads();

  // softmax over k + aggregate with val
  if (tid < 128) {
    int orr = tid, o = orr >> 1;
    float bt = wf[OABT + o];
    float m = -3.4e38f;
#pragma unroll
    for (int kk = 0; kk < 20; ++kk) m = fmaxf(m, lg[orr][kk] + bt);
    float e[20];
    float s = 0.f;
#pragma unroll
    for (int kk = 0; kk < 20; ++kk) { e[kk] = expf(lg[orr][kk] + bt - m); s += e[kk]; }
    float inv = 1.f / s;
    float a = 0.f;
#pragma unroll
    for (int kk = 0; kk < 20; ++kk) a += (e[kk] * inv) * vg[o][kk];
    aggs[orr] = a;
  }
  __syncthreads();

  // y = we @ agg + be ; out = y + iden
  {
    int co = tid & 127, r = tid >> 7;
    float y = wf[OBE + co];
#pragma unroll 8
    for (int o = 0; o < 64; ++o) y += wf[OWET + o * 128 + co] * aggs[o * 2 + r];
    y += idv[co];
    out[((size_t)b * 128 + co) * (size_t)(2 * N_) + 2 * n + r] = y;
  }
}

extern "C" void kernel_launch(void* const* d_in, const int* in_sizes, int n_in,
                              void* d_out, int out_size, void* d_ws, size_t ws_size,
                              hipStream_t stream) {
  (void)in_sizes; (void)n_in; (void)out_size; (void)ws_size;
  InPtrs ip;
  for (int i = 0; i < 38; ++i) ip.p[i] = (const float*)d_in[i];
  char* ws = (char*)d_ws;
  float* wf    = (float*)(ws + OFFB_WF);
  int*   idxb  = (int*)(ws + OFFB_IDX);
  float* qb    = (float*)(ws + OFFB_Q);
  float* kb    = (float*)(ws + OFFB_K);
  float* ubuf  = (float*)(ws + OFFB_U);
  float* vbuf  = (float*)(ws + OFFB_V);
  float* idenb = (float*)(ws + OFFB_IDEN);

  k_prep<<<dim3(256), dim3(256), 0, stream>>>(ip, wf);
  k_mv<<<dim3(128, 8), dim3(256), 0, stream>>>(wf, ip.p[1], ip.p[2], vbuf, idenb);
  k_gemm64<<<dim3(32, 1, 8), dim3(256), 0, stream>>>(wf + OWQT, wf + OBQ, ip.p[2], qb);
  k_gemm64<<<dim3(32, 1, 8), dim3(256), 0, stream>>>(wf + OWKT, wf + OBK, ip.p[1], kb);
  k_gemm64<<<dim3(32, 1, 8), dim3(256), 0, stream>>>(wf + OWUT, wf + OBU, ip.p[3], ubuf);
  k_knn<<<dim3(B_ * N_), dim3(256), 0, stream>>>(ip.p[0], idxb);
  k_attn<<<dim3(B_ * N_), dim3(256), 0, stream>>>(wf, qb, kb, vbuf, ubuf, idenb, idxb,
                                                  ip.p[0], (float*)d_out);
}

// Round 5
// 2058.089 us; speedup vs baseline: 1.5314x; 1.5314x over previous
//
#include <hip/hip_runtime.h>
#include <hip/hip_bf16.h>

constexpr int B_ = 8, N_ = 2048, K_ = 20;
constexpr float EPS_ = 1e-5f;

// ---- weight area offsets (in floats) ----
constexpr int OW1T = 0;                    // W1^T  [512][256]
constexpr int OWST = OW1T + 512 * 256;     // Ws^T  [512][256]
constexpr int OW2T = OWST + 512 * 256;     // W2^T  [256][256]
constexpr int OWQT = OW2T + 256 * 256;     // wq^T  [256][64]
constexpr int OWKT = OWQT + 256 * 64;
constexpr int OWVT = OWKT + 256 * 64;
constexpr int OWUT = OWVT + 256 * 64;
constexpr int OWRT = OWUT + 256 * 64;      // wr^T  [256][128]
constexpr int OWET = OWRT + 256 * 128;     // we^T  [o][co] 64x128
constexpr int OWTC = OWET + 64 * 128;      // am_wt [c][o*2+r] 256x128 (native)
constexpr int OAW1 = OWTC + 256 * 128;     // am_w1 stored [o(64)][c(256)] = am_w1[c][o]
constexpr int OPW1 = OAW1 + 64 * 256;      // pm_w1 [ph][3]
constexpr int OPW2 = OPW1 + 64 * 3;        // pm_w2 [o][c] 64x64 (native)
constexpr int OB1  = OPW2 + 64 * 64;       // mv_b1 [256]
constexpr int OBS2 = OB1 + 256;            // mv_bs + mv_b2 [256]
constexpr int OBQ  = OBS2 + 256;
constexpr int OBK  = OBQ + 64;
constexpr int OBV  = OBK + 64;
constexpr int OBU  = OBV + 64;
constexpr int OBR  = OBU + 64;             // [128]
constexpr int OBE  = OBR + 128;            // [128]
constexpr int OPB1 = OBE + 128;            // [64]
constexpr int OPSC = OPB1 + 64;
constexpr int OPSH = OPSC + 64;
constexpr int OPB2 = OPSH + 64;
constexpr int OASC = OPB2 + 64;            // [256]
constexpr int OASH = OASC + 256;
constexpr int OAB1 = OASH + 256;
constexpr int OABT = OAB1 + 256;           // [64]

// ---- workspace byte offsets (28 MiB total) ----
constexpr size_t OFFB_WF   = 0;
constexpr size_t OFFB_IDX  = (size_t)2 << 20;
constexpr size_t OFFB_Q    = (size_t)4 << 20;
constexpr size_t OFFB_K    = (size_t)8 << 20;
constexpr size_t OFFB_U    = (size_t)12 << 20;
constexpr size_t OFFB_V    = (size_t)16 << 20;
constexpr size_t OFFB_IDEN = (size_t)20 << 20;

struct InPtrs { const float* p[38]; };

// ------------------------------------------------------------------
// Weight prep: transposes + BN folds (all f32)
// ------------------------------------------------------------------
__global__ __launch_bounds__(256) void k_prep(InPtrs in, float* __restrict__ wf) {
  const int tid = blockIdx.x * 256 + threadIdx.x;
  const int nth = gridDim.x * 256;
  const float *mv_w1 = in.p[4], *mv_b1 = in.p[5], *mv_w2 = in.p[6], *mv_b2 = in.p[7],
              *mv_ws = in.p[8], *mv_bs = in.p[9], *wk = in.p[10], *bk = in.p[11],
              *wq = in.p[12], *bq = in.p[13], *wv = in.p[14], *bv = in.p[15],
              *wu = in.p[16], *bu = in.p[17], *pm_w1 = in.p[18], *pm_b1 = in.p[19],
              *pm_g = in.p[20], *pm_be = in.p[21], *pm_m = in.p[22], *pm_v = in.p[23],
              *pm_w2 = in.p[24], *pm_b2 = in.p[25], *am_w1 = in.p[26], *am_b1 = in.p[27],
              *am_g = in.p[28], *am_be = in.p[29], *am_m = in.p[30], *am_v = in.p[31],
              *am_wt = in.p[32], *am_bt = in.p[33], *we = in.p[34], *be = in.p[35],
              *wr = in.p[36], *br = in.p[37];

  for (int i = tid; i < 512 * 256; i += nth) { int c = i >> 8, m = i & 255; wf[OW1T + i] = mv_w1[m * 512 + c]; }
  for (int i = tid; i < 512 * 256; i += nth) { int c = i >> 8, m = i & 255; wf[OWST + i] = mv_ws[m * 512 + c]; }
  for (int i = tid; i < 256 * 256; i += nth) { int c = i >> 8, m = i & 255; wf[OW2T + i] = mv_w2[m * 256 + c]; }
  for (int i = tid; i < 256 * 64; i += nth) { int c = i >> 6, m = i & 63; wf[OWQT + i] = wq[m * 256 + c]; }
  for (int i = tid; i < 256 * 64; i += nth) { int c = i >> 6, m = i & 63; wf[OWKT + i] = wk[m * 256 + c]; }
  for (int i = tid; i < 256 * 64; i += nth) { int c = i >> 6, m = i & 63; wf[OWVT + i] = wv[m * 256 + c]; }
  for (int i = tid; i < 256 * 64; i += nth) { int c = i >> 6, m = i & 63; wf[OWUT + i] = wu[m * 256 + c]; }
  for (int i = tid; i < 256 * 128; i += nth) { int c = i >> 7, m = i & 127; wf[OWRT + i] = wr[m * 256 + c]; }
  for (int i = tid; i < 64 * 128; i += nth) { int o = i >> 7, co = i & 127; wf[OWET + i] = we[co * 64 + o]; }
  for (int i = tid; i < 256 * 128; i += nth) wf[OWTC + i] = am_wt[i];
  for (int i = tid; i < 64 * 256; i += nth) { int o = i >> 8, c = i & 255; wf[OAW1 + i] = am_w1[c * 64 + o]; }
  for (int i = tid; i < 192; i += nth) wf[OPW1 + i] = pm_w1[i];
  for (int i = tid; i < 4096; i += nth) wf[OPW2 + i] = pm_w2[i];
  for (int i = tid; i < 256; i += nth) {
    wf[OB1 + i] = mv_b1[i];
    wf[OBS2 + i] = mv_bs[i] + mv_b2[i];
    float sc = am_g[i] / sqrtf(am_v[i] + EPS_);
    wf[OASC + i] = sc;
    wf[OASH + i] = am_be[i] - am_m[i] * sc;
    wf[OAB1 + i] = am_b1[i];
  }
  for (int i = tid; i < 64; i += nth) {
    wf[OBQ + i] = bq[i]; wf[OBK + i] = bk[i];
    wf[OBV + i] = bv[i]; wf[OBU + i] = bu[i];
    wf[OABT + i] = am_bt[i]; wf[OPB1 + i] = pm_b1[i]; wf[OPB2 + i] = pm_b2[i];
    float sc = pm_g[i] / sqrtf(pm_v[i] + EPS_);
    wf[OPSC + i] = sc;
    wf[OPSH + i] = pm_be[i] - pm_m[i] * sc;
  }
  for (int i = tid; i < 128; i += nth) { wf[OBR + i] = br[i]; wf[OBE + i] = be[i]; }
}

// ------------------------------------------------------------------
// Fused mv-MLP + v/iden projections. One block per (b, 16-col n-tile).
// ------------------------------------------------------------------
__global__ __launch_bounds__(256) void k_mv(const float* __restrict__ wf,
                                            const float* __restrict__ keyf,
                                            const float* __restrict__ qryf,
                                            float* __restrict__ vout,
                                            float* __restrict__ idenout) {
  const int b = blockIdx.y;
  const int n0 = blockIdx.x * 16;
  __shared__ float hidL[256][16];
  __shared__ float valL[256][16];
  __shared__ float wsL[16][64];
  __shared__ float xsL[16][16];
  const int tid = threadIdx.x;
  const int tn = tid & 15, tm = tid >> 4;

  // Phase 1: hid = relu(W1 [key;qry] + b1)
  for (int ms = 0; ms < 4; ++ms) {
    float acc[4] = {};
    for (int kt = 0; kt < 512; kt += 16) {
      for (int i = tid; i < 1024; i += 256) {
        int kk = i >> 6, col = i & 63;
        wsL[kk][col] = wf[OW1T + (size_t)(kt + kk) * 256 + ms * 64 + col];
      }
      {
        int kk = tid >> 4, col = tid & 15;
        int c = kt + kk;
        const float* s = (c < 256) ? keyf : qryf;
        xsL[kk][col] = s[((size_t)b * 256 + (c & 255)) * N_ + n0 + col];
      }
      __syncthreads();
#pragma unroll
      for (int kk = 0; kk < 16; ++kk) {
        float x = xsL[kk][tn];
        float4 w4 = *(const float4*)&wsL[kk][tm * 4];
        acc[0] += w4.x * x; acc[1] += w4.y * x; acc[2] += w4.z * x; acc[3] += w4.w * x;
      }
      __syncthreads();
    }
#pragma unroll
    for (int i = 0; i < 4; ++i)
      hidL[ms * 64 + tm * 4 + i][tn] = fmaxf(acc[i] + wf[OB1 + ms * 64 + tm * 4 + i], 0.f);
  }
  __syncthreads();

  // Phase 2: value = Ws [key;qry] + W2 hid + (bs + b2)
  for (int ms = 0; ms < 4; ++ms) {
    float acc[4] = {};
    for (int kt = 0; kt < 512; kt += 16) {
      for (int i = tid; i < 1024; i += 256) {
        int kk = i >> 6, col = i & 63;
        wsL[kk][col] = wf[OWST + (size_t)(kt + kk) * 256 + ms * 64 + col];
      }
      {
        int kk = tid >> 4, col = tid & 15;
        int c = kt + kk;
        const float* s = (c < 256) ? keyf : qryf;
        xsL[kk][col] = s[((size_t)b * 256 + (c & 255)) * N_ + n0 + col];
      }
      __syncthreads();
#pragma unroll
      for (int kk = 0; kk < 16; ++kk) {
        float x = xsL[kk][tn];
        float4 w4 = *(const float4*)&wsL[kk][tm * 4];
        acc[0] += w4.x * x; acc[1] += w4.y * x; acc[2] += w4.z * x; acc[3] += w4.w * x;
      }
      __syncthreads();
    }
    for (int kt = 0; kt < 256; kt += 16) {
      for (int i = tid; i < 1024; i += 256) {
        int kk = i >> 6, col = i & 63;
        wsL[kk][col] = wf[OW2T + (size_t)(kt + kk) * 256 + ms * 64 + col];
      }
      __syncthreads();
#pragma unroll
      for (int kk = 0; kk < 16; ++kk) {
        float x = hidL[kt + kk][tn];
        float4 w4 = *(const float4*)&wsL[kk][tm * 4];
        acc[0] += w4.x * x; acc[1] += w4.y * x; acc[2] += w4.z * x; acc[3] += w4.w * x;
      }
      __syncthreads();
    }
#pragma unroll
    for (int i = 0; i < 4; ++i)
      valL[ms * 64 + tm * 4 + i][tn] = acc[i] + wf[OBS2 + ms * 64 + tm * 4 + i];
  }
  __syncthreads();

  // Phase 3a: v = Wv value + bv
  {
    float acc[4] = {};
    for (int kt = 0; kt < 256; kt += 16) {
      for (int i = tid; i < 1024; i += 256) {
        int kk = i >> 6, col = i & 63;
        wsL[kk][col] = wf[OWVT + (size_t)(kt + kk) * 64 + col];
      }
      __syncthreads();
#pragma unroll
      for (int kk = 0; kk < 16; ++kk) {
        float x = valL[kt + kk][tn];
        float4 w4 = *(const float4*)&wsL[kk][tm * 4];
        acc[0] += w4.x * x; acc[1] += w4.y * x; acc[2] += w4.z * x; acc[3] += w4.w * x;
      }
      __syncthreads();
    }
#pragma unroll
    for (int i = 0; i < 4; ++i)
      vout[((size_t)b * 64 + tm * 4 + i) * N_ + n0 + tn] = acc[i] + wf[OBV + tm * 4 + i];
  }
  // Phase 3b: iden = Wr value + br
  for (int ms = 0; ms < 2; ++ms) {
    float acc[4] = {};
    for (int kt = 0; kt < 256; kt += 16) {
      for (int i = tid; i < 1024; i += 256) {
        int kk = i >> 6, col = i & 63;
        wsL[kk][col] = wf[OWRT + (size_t)(kt + kk) * 128 + ms * 64 + col];
      }
      __syncthreads();
#pragma unroll
      for (int kk = 0; kk < 16; ++kk) {
        float x = valL[kt + kk][tn];
        float4 w4 = *(const float4*)&wsL[kk][tm * 4];
        acc[0] += w4.x * x; acc[1] += w4.y * x; acc[2] += w4.z * x; acc[3] += w4.w * x;
      }
      __syncthreads();
    }
#pragma unroll
    for (int i = 0; i < 4; ++i)
      idenout[((size_t)b * 128 + ms * 64 + tm * 4 + i) * N_ + n0 + tn] =
          acc[i] + wf[OBR + ms * 64 + tm * 4 + i];
  }
}

// ------------------------------------------------------------------
// q/k/u projections in one launch: blockIdx.y selects the projection.
// ------------------------------------------------------------------
struct Gx { const float* x0; const float* x1; const float* x2;
            float* o0; float* o1; float* o2; };

__global__ __launch_bounds__(256) void k_gemm64x3(const float* __restrict__ wf, Gx g) {
  const int b = blockIdx.z;
  const int n0 = blockIdx.x * 64;
  const int y = blockIdx.y;
  const int wsel = (y == 2) ? 3 : y;
  const float* Wt = wf + OWQT + wsel * (256 * 64);
  const float* bias = wf + OBQ + wsel * 64;
  const float* x = (y == 0) ? g.x0 : (y == 1) ? g.x1 : g.x2;
  float* out = (y == 0) ? g.o0 : (y == 1) ? g.o1 : g.o2;
  __shared__ float ws_[16][64];
  __shared__ float xs_[16][64];
  const int tid = threadIdx.x, tm = tid & 15, tn = tid >> 4;
  float acc[4][4] = {};
  for (int kt = 0; kt < 256; kt += 16) {
    for (int i = tid; i < 1024; i += 256) {
      int kk = i >> 6, col = i & 63;
      ws_[kk][col] = Wt[(size_t)(kt + kk) * 64 + col];
      xs_[kk][col] = x[((size_t)b * 256 + kt + kk) * N_ + n0 + col];
    }
    __syncthreads();
#pragma unroll
    for (int kk = 0; kk < 16; ++kk) {
      float4 x4 = *(const float4*)&xs_[kk][tn * 4];
      float4 w4 = *(const float4*)&ws_[kk][tm * 4];
      float wv[4] = {w4.x, w4.y, w4.z, w4.w};
      float xv[4] = {x4.x, x4.y, x4.z, x4.w};
#pragma unroll
      for (int i = 0; i < 4; ++i)
#pragma unroll
        for (int j = 0; j < 4; ++j) acc[i][j] += wv[i] * xv[j];
    }
    __syncthreads();
  }
#pragma unroll
  for (int i = 0; i < 4; ++i) {
    float bi = bias[tm * 4 + i];
#pragma unroll
    for (int j = 0; j < 4; ++j)
      out[((size_t)b * 64 + tm * 4 + i) * N_ + n0 + tn * 4 + j] = acc[i][j] + bi;
  }
}

// ------------------------------------------------------------------
// Self-KNN, register-resident: each thread owns 8 candidates (f64).
// d2 math identical to the passing version (f64 exact ordering).
// ------------------------------------------------------------------
__global__ __launch_bounds__(256, 4) void k_knn(const float* __restrict__ pos,
                                                int* __restrict__ idxout) {
  const int b = blockIdx.x >> 11, n = blockIdx.x & 2047;
  __shared__ double redd[4];
  __shared__ int redi[4];
  const int tid = threadIdx.x;
  const float* pb = pos + (size_t)b * 3 * N_;
  const double xq = pb[n], yq = pb[N_ + n], zq = pb[2 * N_ + n];
  const double sq = xq * xq + yq * yq + zq * zq;
  double d2[8];
#pragma unroll
  for (int s = 0; s < 8; ++s) {
    int i = tid + s * 256;
    double x = pb[i], y = pb[N_ + i], z = pb[2 * N_ + i];
    double psq = x * x + y * y + z * z;
    double dot = xq * x + yq * y + zq * z;
    d2[s] = (sq + psq) - 2.0 * dot;
  }
  const int lane = tid & 63, wv = tid >> 6;
  for (int r = 0; r < K_; ++r) {
    double bd = d2[0];
    int bi = tid;
#pragma unroll
    for (int s = 1; s < 8; ++s)
      if (d2[s] < bd) { bd = d2[s]; bi = tid + s * 256; }
#pragma unroll
    for (int off = 32; off; off >>= 1) {
      double od = __shfl_down(bd, off);
      int oi = __shfl_down(bi, off);
      if (od < bd || (od == bd && oi < bi)) { bd = od; bi = oi; }
    }
    if (lane == 0) { redd[wv] = bd; redi[wv] = bi; }
    __syncthreads();
    double md = redd[0];
    int mi = redi[0];
#pragma unroll
    for (int w = 1; w < 4; ++w)
      if (redd[w] < md || (redd[w] == md && redi[w] < mi)) { md = redd[w]; mi = redi[w]; }
    if (tid == 0) idxout[((size_t)b * N_ + n) * K_ + r] = mi;
    if ((mi & 255) == tid) d2[mi >> 8] = __builtin_inf();
    __syncthreads();
  }
}

// ------------------------------------------------------------------
// Fused attention tail v2: 40 KB LDS -> 4 blocks/CU, vectorized LDS.
// ------------------------------------------------------------------
__global__ __launch_bounds__(256, 4) void k_attn(
    const float* __restrict__ wf,
    const float* __restrict__ qb, const float* __restrict__ kb,
    const float* __restrict__ vb, const float* __restrict__ ub,
    const float* __restrict__ idenb, const int* __restrict__ idxb,
    const float* __restrict__ pos, float* __restrict__ out) {
  const int b = blockIdx.x >> 11, n = blockIdx.x & 2047;
  const int tid = threadIdx.x;
  __shared__ __align__(16) char smem[40960];
  float* sS   = (float*)smem;            // [64][20] s; later aggs[128]
  float* sVal = (float*)(smem + 5120);   // [64][20] val
  float* sHs  = (float*)(smem + 10240);  // [256][20] h; head hosts idxs/pr* pre-P4
  float* sU   = (float*)(smem + 30720);  // t1s[20][64] then lg[128][20]
  int*   idxs = (int*)(smem + 10240);
  float* prx  = (float*)(smem + 10240 + 80);
  float* pry  = prx + 20;
  float* prz  = pry + 20;
  float* aggs = (float*)smem;

  // P0: neighbor indices
  if (tid < 20) idxs[tid] = idxb[((size_t)b * N_ + n) * K_ + tid] & 2047;
  __syncthreads();

  const int o64 = tid & 63, kslot = tid >> 6, kk0 = kslot * 5;

  // P1: gather + fold q/u terms; pos_rel
  {
    size_t baseq = ((size_t)b * 64 + o64) * N_;
    float qvo = qb[baseq + n];
    float ufo = ub[baseq + n];
    const float* kbp = kb + baseq;
    const float* vbp = vb + baseq;
    const float* ubp = ub + baseq;
#pragma unroll
    for (int t = 0; t < 5; ++t) {
      int kk = kk0 + t;
      int j = idxs[kk];
      float kvv = kbp[j], vvv = vbp[j], uvv = ubp[j];
      float ur = ufo - uvv;
      sS[o64 * 20 + kk] = (qvo - kvv) + ur;
      sVal[o64 * 20 + kk] = vvv + ur;
    }
    if (tid < 20) {
      int j = idxs[tid];
      const float* pp = pos + (size_t)b * 3 * N_;
      prx[tid] = pp[n] - pp[j];
      pry[tid] = pp[N_ + n] - pp[N_ + j];
      prz[tid] = pp[2 * N_ + n] - pp[2 * N_ + j];
    }
  }
  __syncthreads();

  // P2: pos-MLP layer1 + BN + relu -> t1s[20][64] (transposed)
  {
    int ph = o64;
    float w0 = wf[OPW1 + ph * 3], w1 = wf[OPW1 + ph * 3 + 1], w2 = wf[OPW1 + ph * 3 + 2];
    float pb1 = wf[OPB1 + ph], sc = wf[OPSC + ph], sh = wf[OPSH + ph];
#pragma unroll
    for (int t = 0; t < 5; ++t) {
      int kk = kk0 + t;
      float u = pb1 + w0 * prx[kk] + w1 * pry[kk] + w2 * prz[kk];
      sU[kk * 64 + ph] = fmaxf(u * sc + sh, 0.f);
    }
  }
  __syncthreads();

  // P3: pos-MLP layer2 in registers, fold into s/val
  {
    float pes[5];
    float pb2 = wf[OPB2 + o64];
#pragma unroll
    for (int t = 0; t < 5; ++t) pes[t] = pb2;
    const float* w = wf + OPW2 + o64 * 64;
#pragma unroll 4
    for (int c4 = 0; c4 < 16; ++c4) {
      float4 w4 = *(const float4*)(w + c4 * 4);
#pragma unroll
      for (int t = 0; t < 5; ++t) {
        float4 tv = *(const float4*)(sU + (kk0 + t) * 64 + c4 * 4);
        pes[t] += w4.x * tv.x + w4.y * tv.y + w4.z * tv.z + w4.w * tv.w;
      }
    }
#pragma unroll
    for (int t = 0; t < 5; ++t) {
      int idx = o64 * 20 + kk0 + t;
      sS[idx] += pes[t];
      sVal[idx] += pes[t];
    }
  }
  __syncthreads();

  // P4: h = relu(bn(am_w1 @ s + b1)) -> sHs[256][20]
  {
    int c = tid;
    float acc[20];
#pragma unroll
    for (int kk = 0; kk < 20; ++kk) acc[kk] = 0.f;
    const float* w = wf + OAW1 + c;
#pragma unroll 2
    for (int o = 0; o < 64; ++o) {
      float wo = w[o * 256];
      const float2* srow = (const float2*)(sS + o * 20);
#pragma unroll
      for (int j = 0; j < 10; ++j) {
        float2 sv = srow[j];
        acc[2 * j] += wo * sv.x;
        acc[2 * j + 1] += wo * sv.y;
      }
    }
    float sc = wf[OASC + c], sh = wf[OASH + c], b1 = wf[OAB1 + c];
#pragma unroll
    for (int kk = 0; kk < 20; ++kk) acc[kk] = fmaxf((acc[kk] + b1) * sc + sh, 0.f);
    float4* hrow = (float4*)(sHs + c * 20);
#pragma unroll
    for (int q = 0; q < 5; ++q)
      hrow[q] = make_float4(acc[4 * q], acc[4 * q + 1], acc[4 * q + 2], acc[4 * q + 3]);
  }
  __syncthreads();

  // P5: logits -> lg (= sU) [128][20]
  {
    int orr = tid & 127, th = tid >> 7;
    float acc[10];
#pragma unroll
    for (int t = 0; t < 10; ++t) acc[t] = 0.f;
    const float* wt = wf + OWTC + orr;
    if (th == 0) {
#pragma unroll 4
      for (int c = 0; c < 256; ++c) {
        float wv = wt[c * 128];
        const float* hp = sHs + c * 20;
        float4 a0 = *(const float4*)hp;
        float4 a1 = *(const float4*)(hp + 4);
        float2 a2 = *(const float2*)(hp + 8);
        acc[0] += wv * a0.x; acc[1] += wv * a0.y; acc[2] += wv * a0.z; acc[3] += wv * a0.w;
        acc[4] += wv * a1.x; acc[5] += wv * a1.y; acc[6] += wv * a1.z; acc[7] += wv * a1.w;
        acc[8] += wv * a2.x; acc[9] += wv * a2.y;
      }
    } else {
#pragma unroll 4
      for (int c = 0; c < 256; ++c) {
        float wv = wt[c * 128];
        const float* hp = sHs + c * 20 + 10;
        float2 a0 = *(const float2*)hp;
        float4 a1 = *(const float4*)(hp + 2);
        float4 a2 = *(const float4*)(hp + 6);
        acc[0] += wv * a0.x; acc[1] += wv * a0.y;
        acc[2] += wv * a1.x; acc[3] += wv * a1.y; acc[4] += wv * a1.z; acc[5] += wv * a1.w;
        acc[6] += wv * a2.x; acc[7] += wv * a2.y; acc[8] += wv * a2.z; acc[9] += wv * a2.w;
      }
    }
    float* lrow = sU + orr * 20 + th * 10;
#pragma unroll
    for (int t = 0; t < 10; ++t) lrow[t] = acc[t];
  }
  __syncthreads();

  // P6: softmax over k + aggregate with val
  if (tid < 128) {
    int orr = tid, o = orr >> 1;
    float l[20];
    const float4* lr = (const float4*)(sU + orr * 20);
#pragma unroll
    for (int q = 0; q < 5; ++q) {
      float4 v4 = lr[q];
      l[4 * q] = v4.x; l[4 * q + 1] = v4.y; l[4 * q + 2] = v4.z; l[4 * q + 3] = v4.w;
    }
    float bt = wf[OABT + o];
    float m = -3.4e38f;
#pragma unroll
    for (int kk = 0; kk < 20; ++kk) { l[kk] += bt; m = fmaxf(m, l[kk]); }
    float s = 0.f;
#pragma unroll
    for (int kk = 0; kk < 20; ++kk) { l[kk] = expf(l[kk] - m); s += l[kk]; }
    float inv = 1.f / s;
    const float2* vrow = (const float2*)(sVal + o * 20);
    float a = 0.f;
#pragma unroll
    for (int j = 0; j < 10; ++j) {
      float2 vv = vrow[j];
      a += l[2 * j] * vv.x + l[2 * j + 1] * vv.y;
    }
    aggs[orr] = a * inv;
  }
  __syncthreads();

  // P7: y = we @ agg + be + iden
  {
    int co = tid & 127, r = tid >> 7;
    float idv = idenb[((size_t)b * 128 + co) * N_ + n];
    float y = wf[OBE + co];
    const float* w = wf + OWET + co;
#pragma unroll 4
    for (int o = 0; o < 64; ++o) y += w[o * 128] * aggs[o * 2 + r];
    out[((size_t)b * 128 + co) * (size_t)(2 * N_) + 2 * n + r] = y + idv;
  }
}

extern "C" void kernel_launch(void* const* d_in, const int* in_sizes, int n_in,
                              void* d_out, int out_size, void* d_ws, size_t ws_size,
                              hipStream_t stream) {
  (void)in_sizes; (void)n_in; (void)out_size; (void)ws_size;
  InPtrs ip;
  for (int i = 0; i < 38; ++i) ip.p[i] = (const float*)d_in[i];
  char* ws = (char*)d_ws;
  float* wf    = (float*)(ws + OFFB_WF);
  int*   idxb  = (int*)(ws + OFFB_IDX);
  float* qb    = (float*)(ws + OFFB_Q);
  float* kb    = (float*)(ws + OFFB_K);
  float* ubuf  = (float*)(ws + OFFB_U);
  float* vbuf  = (float*)(ws + OFFB_V);
  float* idenb = (float*)(ws + OFFB_IDEN);

  k_prep<<<dim3(256), dim3(256), 0, stream>>>(ip, wf);
  k_mv<<<dim3(128, 8), dim3(256), 0, stream>>>(wf, ip.p[1], ip.p[2], vbuf, idenb);
  Gx g{ip.p[2], ip.p[1], ip.p[3], qb, kb, ubuf};
  k_gemm64x3<<<dim3(32, 3, 8), dim3(256), 0, stream>>>(wf, g);
  k_knn<<<dim3(B_ * N_), dim3(256), 0, stream>>>(ip.p[0], idxb);
  k_attn<<<dim3(B_ * N_), dim3(256), 0, stream>>>(wf, qb, kb, vbuf, ubuf, idenb, idxb,
                                                  ip.p[0], (float*)d_out);
}

// Round 6
// 1945.534 us; speedup vs baseline: 1.6200x; 1.0579x over previous
//
#include <hip/hip_runtime.h>
#include <hip/hip_bf16.h>

constexpr int B_ = 8, N_ = 2048, K_ = 20;
constexpr float EPS_ = 1e-5f;

// ---- weight area offsets (in floats) ----
constexpr int OW1T = 0;                    // W1^T  [512][256]
constexpr int OWST = OW1T + 512 * 256;     // Ws^T  [512][256]
constexpr int OW2T = OWST + 512 * 256;     // W2^T  [256][256]
constexpr int OWQT = OW2T + 256 * 256;     // wq^T  [256][64]
constexpr int OWKT = OWQT + 256 * 64;
constexpr int OWVT = OWKT + 256 * 64;
constexpr int OWUT = OWVT + 256 * 64;
constexpr int OWRT = OWUT + 256 * 64;      // wr^T  [256][128]
constexpr int OWET = OWRT + 256 * 128;     // we^T  [o][co] 64x128
constexpr int OWTC = OWET + 64 * 128;      // am_wt [c][o*2+r] 256x128 (native)
constexpr int OAW1 = OWTC + 256 * 128;     // am_w1^T [o(64)][c(256)]
constexpr int OPW1 = OAW1 + 64 * 256;      // pm_w1 [ph][3]
constexpr int OPW2 = OPW1 + 64 * 3;        // pm_w2 [o][c] 64x64 (native)
constexpr int OB1  = OPW2 + 64 * 64;       // mv_b1 [256]
constexpr int OBS2 = OB1 + 256;            // mv_bs + mv_b2 [256]
constexpr int OBQ  = OBS2 + 256;
constexpr int OBK  = OBQ + 64;
constexpr int OBV  = OBK + 64;
constexpr int OBU  = OBV + 64;
constexpr int OBR  = OBU + 64;             // [128]
constexpr int OBE  = OBR + 128;            // [128]
constexpr int OPB1 = OBE + 128;            // [64]
constexpr int OPSC = OPB1 + 64;
constexpr int OPSH = OPSC + 64;
constexpr int OPB2 = OPSH + 64;
constexpr int OASC = OPB2 + 64;            // [256]
constexpr int OASH = OASC + 256;
constexpr int OAB1 = OASH + 256;
constexpr int OABT = OAB1 + 256;           // [64]

// ---- workspace byte offsets (28 MiB total) ----
constexpr size_t OFFB_WF   = 0;
constexpr size_t OFFB_IDX  = (size_t)2 << 20;
constexpr size_t OFFB_Q    = (size_t)4 << 20;   // [b][n][64]
constexpr size_t OFFB_K    = (size_t)8 << 20;   // [b][n][64]
constexpr size_t OFFB_U    = (size_t)12 << 20;  // [b][n][64]
constexpr size_t OFFB_V    = (size_t)16 << 20;  // [b][n][64]
constexpr size_t OFFB_IDEN = (size_t)20 << 20;  // [b][n][128]

struct InPtrs { const float* p[38]; };

// ------------------------------------------------------------------
// Weight prep: transposes + BN folds (all f32)
// ------------------------------------------------------------------
__global__ __launch_bounds__(256) void k_prep(InPtrs in, float* __restrict__ wf) {
  const int tid = blockIdx.x * 256 + threadIdx.x;
  const int nth = gridDim.x * 256;
  const float *mv_w1 = in.p[4], *mv_b1 = in.p[5], *mv_w2 = in.p[6], *mv_b2 = in.p[7],
              *mv_ws = in.p[8], *mv_bs = in.p[9], *wk = in.p[10], *bk = in.p[11],
              *wq = in.p[12], *bq = in.p[13], *wv = in.p[14], *bv = in.p[15],
              *wu = in.p[16], *bu = in.p[17], *pm_w1 = in.p[18], *pm_b1 = in.p[19],
              *pm_g = in.p[20], *pm_be = in.p[21], *pm_m = in.p[22], *pm_v = in.p[23],
              *pm_w2 = in.p[24], *pm_b2 = in.p[25], *am_w1 = in.p[26], *am_b1 = in.p[27],
              *am_g = in.p[28], *am_be = in.p[29], *am_m = in.p[30], *am_v = in.p[31],
              *am_wt = in.p[32], *am_bt = in.p[33], *we = in.p[34], *be = in.p[35],
              *wr = in.p[36], *br = in.p[37];

  for (int i = tid; i < 512 * 256; i += nth) { int c = i >> 8, m = i & 255; wf[OW1T + i] = mv_w1[m * 512 + c]; }
  for (int i = tid; i < 512 * 256; i += nth) { int c = i >> 8, m = i & 255; wf[OWST + i] = mv_ws[m * 512 + c]; }
  for (int i = tid; i < 256 * 256; i += nth) { int c = i >> 8, m = i & 255; wf[OW2T + i] = mv_w2[m * 256 + c]; }
  for (int i = tid; i < 256 * 64; i += nth) { int c = i >> 6, m = i & 63; wf[OWQT + i] = wq[m * 256 + c]; }
  for (int i = tid; i < 256 * 64; i += nth) { int c = i >> 6, m = i & 63; wf[OWKT + i] = wk[m * 256 + c]; }
  for (int i = tid; i < 256 * 64; i += nth) { int c = i >> 6, m = i & 63; wf[OWVT + i] = wv[m * 256 + c]; }
  for (int i = tid; i < 256 * 64; i += nth) { int c = i >> 6, m = i & 63; wf[OWUT + i] = wu[m * 256 + c]; }
  for (int i = tid; i < 256 * 128; i += nth) { int c = i >> 7, m = i & 127; wf[OWRT + i] = wr[m * 256 + c]; }
  for (int i = tid; i < 64 * 128; i += nth) { int o = i >> 7, co = i & 127; wf[OWET + i] = we[co * 64 + o]; }
  for (int i = tid; i < 256 * 128; i += nth) wf[OWTC + i] = am_wt[i];
  for (int i = tid; i < 64 * 256; i += nth) { int o = i >> 8, c = i & 255; wf[OAW1 + i] = am_w1[c * 64 + o]; }
  for (int i = tid; i < 192; i += nth) wf[OPW1 + i] = pm_w1[i];
  for (int i = tid; i < 4096; i += nth) wf[OPW2 + i] = pm_w2[i];
  for (int i = tid; i < 256; i += nth) {
    wf[OB1 + i] = mv_b1[i];
    wf[OBS2 + i] = mv_bs[i] + mv_b2[i];
    float sc = am_g[i] / sqrtf(am_v[i] + EPS_);
    wf[OASC + i] = sc;
    wf[OASH + i] = am_be[i] - am_m[i] * sc;
    wf[OAB1 + i] = am_b1[i];
  }
  for (int i = tid; i < 64; i += nth) {
    wf[OBQ + i] = bq[i]; wf[OBK + i] = bk[i];
    wf[OBV + i] = bv[i]; wf[OBU + i] = bu[i];
    wf[OABT + i] = am_bt[i]; wf[OPB1 + i] = pm_b1[i]; wf[OPB2 + i] = pm_b2[i];
    float sc = pm_g[i] / sqrtf(pm_v[i] + EPS_);
    wf[OPSC + i] = sc;
    wf[OPSH + i] = pm_be[i] - pm_m[i] * sc;
  }
  for (int i = tid; i < 128; i += nth) { wf[OBR + i] = br[i]; wf[OBE + i] = be[i]; }
}

// ------------------------------------------------------------------
// Fused mv-MLP + v/iden projections. Outputs transposed: [b][n][ch].
// ------------------------------------------------------------------
__global__ __launch_bounds__(256) void k_mv(const float* __restrict__ wf,
                                            const float* __restrict__ keyf,
                                            const float* __restrict__ qryf,
                                            float* __restrict__ vout,
                                            float* __restrict__ idenout) {
  const int b = blockIdx.y;
  const int n0 = blockIdx.x * 16;
  __shared__ float hidL[256][16];
  __shared__ float valL[256][16];
  __shared__ float wsL[16][64];
  __shared__ float xsL[16][16];
  const int tid = threadIdx.x;
  const int tn = tid & 15, tm = tid >> 4;

  // Phase 1: hid = relu(W1 [key;qry] + b1)
  for (int ms = 0; ms < 4; ++ms) {
    float acc[4] = {};
    for (int kt = 0; kt < 512; kt += 16) {
      for (int i = tid; i < 1024; i += 256) {
        int kk = i >> 6, col = i & 63;
        wsL[kk][col] = wf[OW1T + (size_t)(kt + kk) * 256 + ms * 64 + col];
      }
      {
        int kk = tid >> 4, col = tid & 15;
        int c = kt + kk;
        const float* s = (c < 256) ? keyf : qryf;
        xsL[kk][col] = s[((size_t)b * 256 + (c & 255)) * N_ + n0 + col];
      }
      __syncthreads();
#pragma unroll
      for (int kk = 0; kk < 16; ++kk) {
        float x = xsL[kk][tn];
        float4 w4 = *(const float4*)&wsL[kk][tm * 4];
        acc[0] += w4.x * x; acc[1] += w4.y * x; acc[2] += w4.z * x; acc[3] += w4.w * x;
      }
      __syncthreads();
    }
#pragma unroll
    for (int i = 0; i < 4; ++i)
      hidL[ms * 64 + tm * 4 + i][tn] = fmaxf(acc[i] + wf[OB1 + ms * 64 + tm * 4 + i], 0.f);
  }
  __syncthreads();

  // Phase 2: value = Ws [key;qry] + W2 hid + (bs + b2)
  for (int ms = 0; ms < 4; ++ms) {
    float acc[4] = {};
    for (int kt = 0; kt < 512; kt += 16) {
      for (int i = tid; i < 1024; i += 256) {
        int kk = i >> 6, col = i & 63;
        wsL[kk][col] = wf[OWST + (size_t)(kt + kk) * 256 + ms * 64 + col];
      }
      {
        int kk = tid >> 4, col = tid & 15;
        int c = kt + kk;
        const float* s = (c < 256) ? keyf : qryf;
        xsL[kk][col] = s[((size_t)b * 256 + (c & 255)) * N_ + n0 + col];
      }
      __syncthreads();
#pragma unroll
      for (int kk = 0; kk < 16; ++kk) {
        float x = xsL[kk][tn];
        float4 w4 = *(const float4*)&wsL[kk][tm * 4];
        acc[0] += w4.x * x; acc[1] += w4.y * x; acc[2] += w4.z * x; acc[3] += w4.w * x;
      }
      __syncthreads();
    }
    for (int kt = 0; kt < 256; kt += 16) {
      for (int i = tid; i < 1024; i += 256) {
        int kk = i >> 6, col = i & 63;
        wsL[kk][col] = wf[OW2T + (size_t)(kt + kk) * 256 + ms * 64 + col];
      }
      __syncthreads();
#pragma unroll
      for (int kk = 0; kk < 16; ++kk) {
        float x = hidL[kt + kk][tn];
        float4 w4 = *(const float4*)&wsL[kk][tm * 4];
        acc[0] += w4.x * x; acc[1] += w4.y * x; acc[2] += w4.z * x; acc[3] += w4.w * x;
      }
      __syncthreads();
    }
#pragma unroll
    for (int i = 0; i < 4; ++i)
      valL[ms * 64 + tm * 4 + i][tn] = acc[i] + wf[OBS2 + ms * 64 + tm * 4 + i];
  }
  __syncthreads();

  // Phase 3a: v = Wv value + bv  -> vout[b][n][64]
  {
    float acc[4] = {};
    for (int kt = 0; kt < 256; kt += 16) {
      for (int i = tid; i < 1024; i += 256) {
        int kk = i >> 6, col = i & 63;
        wsL[kk][col] = wf[OWVT + (size_t)(kt + kk) * 64 + col];
      }
      __syncthreads();
#pragma unroll
      for (int kk = 0; kk < 16; ++kk) {
        float x = valL[kt + kk][tn];
        float4 w4 = *(const float4*)&wsL[kk][tm * 4];
        acc[0] += w4.x * x; acc[1] += w4.y * x; acc[2] += w4.z * x; acc[3] += w4.w * x;
      }
      __syncthreads();
    }
    *(float4*)(vout + ((size_t)b * N_ + n0 + tn) * 64 + tm * 4) =
        make_float4(acc[0] + wf[OBV + tm * 4], acc[1] + wf[OBV + tm * 4 + 1],
                    acc[2] + wf[OBV + tm * 4 + 2], acc[3] + wf[OBV + tm * 4 + 3]);
  }
  // Phase 3b: iden = Wr value + br -> idenout[b][n][128]
  for (int ms = 0; ms < 2; ++ms) {
    float acc[4] = {};
    for (int kt = 0; kt < 256; kt += 16) {
      for (int i = tid; i < 1024; i += 256) {
        int kk = i >> 6, col = i & 63;
        wsL[kk][col] = wf[OWRT + (size_t)(kt + kk) * 128 + ms * 64 + col];
      }
      __syncthreads();
#pragma unroll
      for (int kk = 0; kk < 16; ++kk) {
        float x = valL[kt + kk][tn];
        float4 w4 = *(const float4*)&wsL[kk][tm * 4];
        acc[0] += w4.x * x; acc[1] += w4.y * x; acc[2] += w4.z * x; acc[3] += w4.w * x;
      }
      __syncthreads();
    }
    int m = ms * 64 + tm * 4;
    *(float4*)(idenout + ((size_t)b * N_ + n0 + tn) * 128 + m) =
        make_float4(acc[0] + wf[OBR + m], acc[1] + wf[OBR + m + 1],
                    acc[2] + wf[OBR + m + 2], acc[3] + wf[OBR + m + 3]);
  }
}

// ------------------------------------------------------------------
// q/k/u projections, one launch; outputs transposed [b][n][64].
// ------------------------------------------------------------------
struct Gx { const float* x0; const float* x1; const float* x2;
            float* o0; float* o1; float* o2; };

__global__ __launch_bounds__(256) void k_gemm64x3(const float* __restrict__ wf, Gx g) {
  const int b = blockIdx.z;
  const int n0 = blockIdx.x * 64;
  const int y = blockIdx.y;
  const int wsel = (y == 2) ? 3 : y;
  const float* Wt = wf + OWQT + wsel * (256 * 64);
  const float* bias = wf + OBQ + wsel * 64;
  const float* x = (y == 0) ? g.x0 : (y == 1) ? g.x1 : g.x2;
  float* out = (y == 0) ? g.o0 : (y == 1) ? g.o1 : g.o2;
  __shared__ float ws_[16][64];
  __shared__ float xs_[16][64];
  const int tid = threadIdx.x, tm = tid & 15, tn = tid >> 4;
  float acc[4][4] = {};
  for (int kt = 0; kt < 256; kt += 16) {
    for (int i = tid; i < 1024; i += 256) {
      int kk = i >> 6, col = i & 63;
      ws_[kk][col] = Wt[(size_t)(kt + kk) * 64 + col];
      xs_[kk][col] = x[((size_t)b * 256 + kt + kk) * N_ + n0 + col];
    }
    __syncthreads();
#pragma unroll
    for (int kk = 0; kk < 16; ++kk) {
      float4 x4 = *(const float4*)&xs_[kk][tn * 4];
      float4 w4 = *(const float4*)&ws_[kk][tm * 4];
      float wv[4] = {w4.x, w4.y, w4.z, w4.w};
      float xv[4] = {x4.x, x4.y, x4.z, x4.w};
#pragma unroll
      for (int i = 0; i < 4; ++i)
#pragma unroll
        for (int j = 0; j < 4; ++j) acc[i][j] += wv[i] * xv[j];
    }
    __syncthreads();
  }
#pragma unroll
  for (int j = 0; j < 4; ++j) {
    *(float4*)(out + ((size_t)b * N_ + n0 + tn * 4 + j) * 64 + tm * 4) =
        make_float4(acc[0][j] + bias[tm * 4], acc[1][j] + bias[tm * 4 + 1],
                    acc[2][j] + bias[tm * 4 + 2], acc[3][j] + bias[tm * 4 + 3]);
  }
}

// ------------------------------------------------------------------
// Self-KNN, register-resident, 1 barrier per round.
// ------------------------------------------------------------------
__global__ __launch_bounds__(256, 4) void k_knn(const float* __restrict__ pos,
                                                int* __restrict__ idxout) {
  const int b = blockIdx.x >> 11, n = blockIdx.x & 2047;
  __shared__ double redd[2][4];
  __shared__ int redi[2][4];
  const int tid = threadIdx.x;
  const float* pb = pos + (size_t)b * 3 * N_;
  const double xq = pb[n], yq = pb[N_ + n], zq = pb[2 * N_ + n];
  const double sq = xq * xq + yq * yq + zq * zq;
  double d2[8];
#pragma unroll
  for (int s = 0; s < 8; ++s) {
    int i = tid + s * 256;
    double x = pb[i], y = pb[N_ + i], z = pb[2 * N_ + i];
    double psq = x * x + y * y + z * z;
    double dot = xq * x + yq * y + zq * z;
    d2[s] = (sq + psq) - 2.0 * dot;
  }
  const int lane = tid & 63, wv = tid >> 6;
  for (int r = 0; r < K_; ++r) {
    double bd = d2[0];
    int bi = tid;
#pragma unroll
    for (int s = 1; s < 8; ++s)
      if (d2[s] < bd) { bd = d2[s]; bi = tid + s * 256; }
#pragma unroll
    for (int off = 32; off; off >>= 1) {
      double od = __shfl_down(bd, off);
      int oi = __shfl_down(bi, off);
      if (od < bd || (od == bd && oi < bi)) { bd = od; bi = oi; }
    }
    int ph = r & 1;
    if (lane == 0) { redd[ph][wv] = bd; redi[ph][wv] = bi; }
    __syncthreads();
    double md = redd[ph][0];
    int mi = redi[ph][0];
#pragma unroll
    for (int w = 1; w < 4; ++w)
      if (redd[ph][w] < md || (redd[ph][w] == md && redi[ph][w] < mi)) { md = redd[ph][w]; mi = redi[ph][w]; }
    if (tid == 0) idxout[((size_t)b * N_ + n) * K_ + r] = mi;
    if ((mi & 255) == tid) d2[mi >> 8] = __builtin_inf();
  }
}

// ------------------------------------------------------------------
// Fused attention tail v3: transposed inputs, conflict-free LDS,
// register-tiled P4/P5. 36.9 KB LDS -> 4 blocks/CU.
// LDS float-index map:
//   sS   [20][65]  @ 0      (dead after P4)      \ lg [20][129] @ 0 (P5..P6)
//   t1s  [20][64]  @ 1300   (dead after P3)      /
//   sVal [20][65]  @ 2580   (live to P6)
//   sHs  [20][260] @ 3880   (P4 -> P5)
//   aggs [128]     @ 9080
// ------------------------------------------------------------------
__global__ __launch_bounds__(256, 4) void k_attn(
    const float* __restrict__ wf,
    const float* __restrict__ qb, const float* __restrict__ kb,
    const float* __restrict__ vb, const float* __restrict__ ub,
    const float* __restrict__ idenb, const int* __restrict__ idxb,
    const float* __restrict__ pos, float* __restrict__ out) {
  const int b = blockIdx.x >> 11, n = blockIdx.x & 2047;
  const int tid = threadIdx.x;
  __shared__ __align__(16) float smem[9216];
  float* sS   = smem;                 // [20][65]
  float* t1s  = smem + 1300;          // [20][64]
  float* lg   = smem;                 // [20][129] overlays sS+t1s
  float* sVal = smem + 2580;          // [20][65]
  float* sHs  = smem + 3880;          // [20][260]
  float* aggs = smem + 9080;          // [128]
  __shared__ int idxs[20];
  __shared__ float prx[20], pry[20], prz[20];

  // P0
  if (tid < 20) idxs[tid] = idxb[((size_t)b * N_ + n) * K_ + tid] & 2047;
  __syncthreads();

  const int o64 = tid & 63, kslot = tid >> 6, kk0 = kslot * 5;

  // P1: coalesced gathers ([b][n][64] layouts), fold q/u terms
  {
    size_t rowq = ((size_t)b * N_ + n) * 64;
    float qvo = qb[rowq + o64];
    float ufo = ub[rowq + o64];
#pragma unroll
    for (int t = 0; t < 5; ++t) {
      int kk = kk0 + t;
      int j = idxs[kk];
      size_t rowj = ((size_t)b * N_ + j) * 64;
      float kvv = kb[rowj + o64], vvv = vb[rowj + o64], uvv = ub[rowj + o64];
      float ur = ufo - uvv;
      sS[kk * 65 + o64] = (qvo - kvv) + ur;
      sVal[kk * 65 + o64] = vvv + ur;
    }
    if (tid < 20) {
      int j = idxs[tid];
      const float* pp = pos + (size_t)b * 3 * N_;
      prx[tid] = pp[n] - pp[j];
      pry[tid] = pp[N_ + n] - pp[N_ + j];
      prz[tid] = pp[2 * N_ + n] - pp[2 * N_ + j];
    }
  }
  __syncthreads();

  // P2: pos-MLP layer1 + BN + relu -> t1s[kk][ph]
  {
    int ph = o64;
    float w0 = wf[OPW1 + ph * 3], w1 = wf[OPW1 + ph * 3 + 1], w2 = wf[OPW1 + ph * 3 + 2];
    float pb1 = wf[OPB1 + ph], sc = wf[OPSC + ph], sh = wf[OPSH + ph];
#pragma unroll
    for (int t = 0; t < 5; ++t) {
      int kk = kk0 + t;
      float u = pb1 + w0 * prx[kk] + w1 * pry[kk] + w2 * prz[kk];
      t1s[kk * 64 + ph] = fmaxf(u * sc + sh, 0.f);
    }
  }
  __syncthreads();

  // P3: pos-MLP layer2 in registers, fold into s/val
  {
    float pes[5];
    float pb2 = wf[OPB2 + o64];
#pragma unroll
    for (int t = 0; t < 5; ++t) pes[t] = pb2;
    const float* w = wf + OPW2 + o64 * 64;
#pragma unroll 4
    for (int c4 = 0; c4 < 16; ++c4) {
      float4 w4 = *(const float4*)(w + c4 * 4);
#pragma unroll
      for (int t = 0; t < 5; ++t) {
        float4 tv = *(const float4*)(t1s + (kk0 + t) * 64 + c4 * 4);
        pes[t] += w4.x * tv.x + w4.y * tv.y + w4.z * tv.z + w4.w * tv.w;
      }
    }
#pragma unroll
    for (int t = 0; t < 5; ++t) {
      int idx = (kk0 + t) * 65 + o64;
      sS[idx] += pes[t];
      sVal[idx] += pes[t];
    }
  }
  __syncthreads();

  // P4: h = relu(bn(am_w1 @ s + b1)), tiled 4c x 5kk per thread
  {
    const int cg = tid >> 2, kg = tid & 3;          // c = cg*4+i, kk = kg*5+t
    float acc[4][5];
#pragma unroll
    for (int i = 0; i < 4; ++i)
#pragma unroll
      for (int t = 0; t < 5; ++t) acc[i][t] = 0.f;
    const float* w = wf + OAW1 + cg * 4;            // aw1T[o][256]
#pragma unroll 4
    for (int o = 0; o < 64; ++o) {
      float4 w4 = *(const float4*)(w + o * 256);
      float wv[4] = {w4.x, w4.y, w4.z, w4.w};
#pragma unroll
      for (int t = 0; t < 5; ++t) {
        float sv = sS[(kg * 5 + t) * 65 + o];
#pragma unroll
        for (int i = 0; i < 4; ++i) acc[i][t] += wv[i] * sv;
      }
    }
#pragma unroll
    for (int t = 0; t < 5; ++t) {
      float hv[4];
#pragma unroll
      for (int i = 0; i < 4; ++i) {
        int c = cg * 4 + i;
        hv[i] = fmaxf((acc[i][t] + wf[OAB1 + c]) * wf[OASC + c] + wf[OASH + c], 0.f);
      }
      *(float4*)(sHs + (kg * 5 + t) * 260 + cg * 4) = make_float4(hv[0], hv[1], hv[2], hv[3]);
    }
  }
  __syncthreads();

  // P5: logits, tiled 2or x 5kk per thread -> lg[kk][129]
  {
    const int og = tid >> 2, kg = tid & 3;          // or = og*2+{0,1}, kk = kg*5+t
    const int or0 = og * 2;
    float acc0[5], acc1[5];
#pragma unroll
    for (int t = 0; t < 5; ++t) { acc0[t] = 0.f; acc1[t] = 0.f; }
    const float* wt = wf + OWTC + or0;
#pragma unroll 2
    for (int c4 = 0; c4 < 64; ++c4) {
      float4 h4[5];
#pragma unroll
      for (int t = 0; t < 5; ++t)
        h4[t] = *(const float4*)(sHs + (kg * 5 + t) * 260 + c4 * 4);
      float2 wt2[4];
#pragma unroll
      for (int i = 0; i < 4; ++i) wt2[i] = *(const float2*)(wt + (c4 * 4 + i) * 128);
#pragma unroll
      for (int t = 0; t < 5; ++t) {
        acc0[t] += h4[t].x * wt2[0].x + h4[t].y * wt2[1].x + h4[t].z * wt2[2].x + h4[t].w * wt2[3].x;
        acc1[t] += h4[t].x * wt2[0].y + h4[t].y * wt2[1].y + h4[t].z * wt2[2].y + h4[t].w * wt2[3].y;
      }
    }
#pragma unroll
    for (int t = 0; t < 5; ++t) {
      lg[(kg * 5 + t) * 129 + or0] = acc0[t];
      lg[(kg * 5 + t) * 129 + or0 + 1] = acc1[t];
    }
  }
  __syncthreads();

  // P6: softmax over k + aggregate with val
  if (tid < 128) {
    int orr = tid, o = orr >> 1;
    float l[20];
#pragma unroll
    for (int kk = 0; kk < 20; ++kk) l[kk] = lg[kk * 129 + orr];
    float bt = wf[OABT + o];
    float m = -3.4e38f;
#pragma unroll
    for (int kk = 0; kk < 20; ++kk) { l[kk] += bt; m = fmaxf(m, l[kk]); }
    float s = 0.f;
#pragma unroll
    for (int kk = 0; kk < 20; ++kk) { l[kk] = expf(l[kk] - m); s += l[kk]; }
    float inv = 1.f / s;
    float a = 0.f;
#pragma unroll
    for (int kk = 0; kk < 20; ++kk) a += l[kk] * sVal[kk * 65 + o];
    aggs[orr] = a * inv;
  }
  __syncthreads();

  // P7: y = we @ agg + be + iden
  {
    int co = tid & 127, r = tid >> 7;
    float idv = idenb[((size_t)b * N_ + n) * 128 + co];
    float y = wf[OBE + co];
    const float* w = wf + OWET + co;
#pragma unroll 4
    for (int o = 0; o < 64; ++o) y += w[o * 128] * aggs[o * 2 + r];
    out[((size_t)b * 128 + co) * (size_t)(2 * N_) + 2 * n + r] = y + idv;
  }
}

extern "C" void kernel_launch(void* const* d_in, const int* in_sizes, int n_in,
                              void* d_out, int out_size, void* d_ws, size_t ws_size,
                              hipStream_t stream) {
  (void)in_sizes; (void)n_in; (void)out_size; (void)ws_size;
  InPtrs ip;
  for (int i = 0; i < 38; ++i) ip.p[i] = (const float*)d_in[i];
  char* ws = (char*)d_ws;
  float* wf    = (float*)(ws + OFFB_WF);
  int*   idxb  = (int*)(ws + OFFB_IDX);
  float* qb    = (float*)(ws + OFFB_Q);
  float* kb    = (float*)(ws + OFFB_K);
  float* ubuf  = (float*)(ws + OFFB_U);
  float* vbuf  = (float*)(ws + OFFB_V);
  float* idenb = (float*)(ws + OFFB_IDEN);

  k_prep<<<dim3(256), dim3(256), 0, stream>>>(ip, wf);
  k_mv<<<dim3(128, 8), dim3(256), 0, stream>>>(wf, ip.p[1], ip.p[2], vbuf, idenb);
  Gx g{ip.p[2], ip.p[1], ip.p[3], qb, kb, ubuf};
  k_gemm64x3<<<dim3(32, 3, 8), dim3(256), 0, stream>>>(wf, g);
  k_knn<<<dim3(B_ * N_), dim3(256), 0, stream>>>(ip.p[0], idxb);
  k_attn<<<dim3(B_ * N_), dim3(256), 0, stream>>>(wf, qb, kb, vbuf, ubuf, idenb, idxb,
                                                  ip.p[0], (float*)d_out);
}